// Round 4
// baseline (159.976 us; speedup 1.0000x reference)
//
#include <hip/hip_runtime.h>
#include <hip/hip_bf16.h>
#include <float.h>

#define DIN   768
#define DSAE  16384
#define K_    32
#define KTOT  2304
#define TD    12288   // 16*768
#define KSPLIT 8
#define KLEN   288
#define KC     32
#define NCH    9
#define SB     512
#define WSTR   36

#define FMA4(ACC, S, A) { ACC.x += (S) * (A).x; ACC.y += (S) * (A).y; \
                          ACC.z += (S) * (A).z; ACC.w += (S) * (A).w; }

__device__ __forceinline__ int aidx(int k, int b) {   // XOR-swizzled A_lds layout
    return k * 32 + (b ^ ((k & 7) << 2));
}

// ---- Kernel 1: fused prep + encode GEMM (K-split x8, 512s x 32b tile) ----
__global__ __launch_bounds__(256, 1) void enc_kernel(
    const float* __restrict__ x,      // (32,16,768)
    const float* __restrict__ W,      // conv_w (16384 x 2304)
    float* __restrict__ partial)      // (8 x 32 x 16384)
{
    __shared__ float Wt[SB * WSTR];      // 73728 B
    __shared__ float A_lds[KLEN * 32];   // 36864 B, swizzled via aidx()

    const int tid  = threadIdx.x;
    const int ks   = blockIdx.x & 7;
    const int s0   = (blockIdx.x >> 3) * SB;
    const int koff = ks * KLEN;
    const int d0   = ks * 96;
    const int l    = tid & 63;
    const int w    = tid >> 6;

    // W chunk-0 prefetch issued first (flies under the A-slice build)
    float4 wreg[16];
    #pragma unroll
    for (int i = 0; i < 16; ++i) {
        int f4 = tid + (i << 8);
        int row = f4 >> 3, c = (f4 & 7) << 2;
        wreg[i] = *(const float4*)&W[(size_t)(s0 + row) * KTOT + koff + c];
    }

    // Build A-slice from x: units (b, d-quad): 32 x 24 = 768, 3 per thread.
    // A[k][b]: k_local=(dd*3+j); u0=S-x[b,15,d], u1=S, u2=S-x[b,0,d]
    #pragma unroll
    for (int u = 0; u < 3; ++u) {
        int unit = u * 256 + tid;
        int b  = unit / 24;
        int dq = unit - b * 24;
        const float* xp = x + (size_t)b * TD + d0 + dq * 4;
        float4 S = {0.f, 0.f, 0.f, 0.f}, x0 = S, xl = S;
        #pragma unroll
        for (int t = 0; t < 16; ++t) {
            float4 v = *(const float4*)&xp[t * DIN];
            if (t == 0)  x0 = v;
            if (t == 15) xl = v;
            S.x += v.x; S.y += v.y; S.z += v.z; S.w += v.w;
        }
        float sv[4]  = {S.x, S.y, S.z, S.w};
        float x0v[4] = {x0.x, x0.y, x0.z, x0.w};
        float xlv[4] = {xl.x, xl.y, xl.z, xl.w};
        const int kb = dq * 12;
        #pragma unroll
        for (int c = 0; c < 4; ++c) {
            int k = kb + c * 3;
            A_lds[aidx(k + 0, b)] = sv[c] - xlv[c];
            A_lds[aidx(k + 1, b)] = sv[c];
            A_lds[aidx(k + 2, b)] = sv[c] - x0v[c];
        }
    }

    float4 acc0[8], acc1[8];
    #pragma unroll
    for (int m = 0; m < 8; ++m) {
        acc0[m] = make_float4(0.f, 0.f, 0.f, 0.f);
        acc1[m] = make_float4(0.f, 0.f, 0.f, 0.f);
    }

    #pragma unroll 1
    for (int ch = 0; ch < NCH; ++ch) {
        __syncthreads();                 // A_lds ready (ch0) / prev compute done
        #pragma unroll
        for (int i = 0; i < 16; ++i) {
            int f4 = tid + (i << 8);
            int row = f4 >> 3, c = (f4 & 7) << 2;
            *(float4*)&Wt[row * WSTR + c] = wreg[i];
        }
        __syncthreads();

        if (ch + 1 < NCH) {              // prefetch next W chunk under compute
            const int kc = (ch + 1) * KC;
            #pragma unroll
            for (int i = 0; i < 16; ++i) {
                int f4 = tid + (i << 8);
                int row = f4 >> 3, c = (f4 & 7) << 2;
                wreg[i] = *(const float4*)&W[(size_t)(s0 + row) * KTOT + koff + kc + c];
            }
        }

        #pragma unroll
        for (int g = 0; g < 8; ++g) {
            const int kk0 = g << 2;
            float4 a0[4], a1[4];
            #pragma unroll
            for (int d = 0; d < 4; ++d) {
                const int k = ch * KC + kk0 + d;
                a0[d] = *(const float4*)&A_lds[aidx(k, w << 3)];
                a1[d] = *(const float4*)&A_lds[aidx(k, (w << 3) + 4)];
            }
            #pragma unroll
            for (int m = 0; m < 8; ++m) {
                float4 wv = *(const float4*)&Wt[(l + (m << 6)) * WSTR + kk0];
                FMA4(acc0[m], wv.x, a0[0]); FMA4(acc0[m], wv.y, a0[1]);
                FMA4(acc0[m], wv.z, a0[2]); FMA4(acc0[m], wv.w, a0[3]);
                FMA4(acc1[m], wv.x, a1[0]); FMA4(acc1[m], wv.y, a1[1]);
                FMA4(acc1[m], wv.z, a1[2]); FMA4(acc1[m], wv.w, a1[3]);
            }
        }
    }

    float* pb = partial + (size_t)(ks * 32 + (w << 3)) * DSAE + s0 + l;
    #pragma unroll
    for (int m = 0; m < 8; ++m) {
        const int so = m << 6;
        pb[(size_t)0 * DSAE + so] = acc0[m].x;
        pb[(size_t)1 * DSAE + so] = acc0[m].y;
        pb[(size_t)2 * DSAE + so] = acc0[m].z;
        pb[(size_t)3 * DSAE + so] = acc0[m].w;
        pb[(size_t)4 * DSAE + so] = acc1[m].x;
        pb[(size_t)5 * DSAE + so] = acc1[m].y;
        pb[(size_t)6 * DSAE + so] = acc1[m].z;
        pb[(size_t)7 * DSAE + so] = acc1[m].w;
    }
}

// ---- Kernel 2: combine K-splits + bias, zero z, per-slice exact top-32 ----
// grid 256 = 32 rows x 8 slices of 2048 cols; pre never materialized.
__global__ __launch_bounds__(256, 1) void combine_topk_kernel(
    const float* __restrict__ partial,
    const float* __restrict__ b_enc,
    float* __restrict__ z,
    float* __restrict__ cand_val,     // (32*8*32)
    int*   __restrict__ cand_idx,
    float* __restrict__ out0)
{
    __shared__ float wv[4];
    __shared__ int   wi[4];

    const int t  = threadIdx.x;
    const int b  = blockIdx.x >> 3;
    const int sl = blockIdx.x & 7;
    const int c0 = sl * 2048;

    float av[8]; int ai[8];
    #pragma unroll
    for (int i = 0; i < 8; ++i) {
        const int col = c0 + t + (i << 8);
        float s = b_enc[col];
        #pragma unroll
        for (int ks = 0; ks < KSPLIT; ++ks)
            s += partial[(size_t)(ks * 32 + b) * DSAE + col];
        av[i] = s; ai[i] = col;
        z[(size_t)b * DSAE + col] = 0.f;
    }
    if (blockIdx.x == 0 && t == 0) *out0 = 0.f;

    for (int k = 0; k < K_; ++k) {
        float m = -FLT_MAX; int mi = 0x7FFFFFFF;
        #pragma unroll
        for (int i = 0; i < 8; ++i)
            if (av[i] > m) { m = av[i]; mi = ai[i]; }   // idx asc within thread (ai increasing)
        #pragma unroll
        for (int off = 1; off < 64; off <<= 1) {
            float ov = __shfl_xor(m,  off, 64);
            int   oi = __shfl_xor(mi, off, 64);
            if (ov > m || (ov == m && oi < mi)) { m = ov; mi = oi; }
        }
        if ((t & 63) == 0) { wv[t >> 6] = m; wi[t >> 6] = mi; }
        __syncthreads();
        float gv = wv[0]; int gi = wi[0];
        #pragma unroll
        for (int q = 1; q < 4; ++q) {
            float ov = wv[q]; int oi = wi[q];
            if (ov > gv || (ov == gv && oi < gi)) { gv = ov; gi = oi; }
        }
        if (t == 0) {
            cand_val[(blockIdx.x << 5) + k] = gv;
            cand_idx[(blockIdx.x << 5) + k] = gi;
        }
        #pragma unroll
        for (int i = 0; i < 8; ++i)
            if (ai[i] == gi) av[i] = -FLT_MAX;
        __syncthreads();
    }
}

// ---- Kernel 3: exact global top-32 from 256 candidates/row; scatter z/sel ----
__global__ __launch_bounds__(256, 1) void select_kernel(
    const float* __restrict__ cand_val,
    const int*   __restrict__ cand_idx,
    float* __restrict__ z,
    float* __restrict__ sel_val,
    int*   __restrict__ sel_idx)
{
    __shared__ float cv[256];
    __shared__ int   ci[256];
    const int t = threadIdx.x;
    const int b = blockIdx.x;

    float v  = cand_val[(b << 8) + t];
    int   ix = cand_idx[(b << 8) + t];
    cv[t] = v; ci[t] = ix;
    __syncthreads();

    int rank = 0;
    #pragma unroll 8
    for (int j = 0; j < 256; ++j) {
        float vj = cv[j]; int ij = ci[j];
        rank += (vj > v || (vj == v && ij < ix)) ? 1 : 0;
    }
    if (rank < K_) {
        float val = v > 0.f ? v : 0.f;
        z[(size_t)b * DSAE + ix] = val;
        sel_val[(b << 5) + rank] = val;
        sel_idx[(b << 5) + rank] = ix;
    }
}

// ---- Kernel 4: sparse decode + fused sq-err, loss via one atomic/block ----
__global__ __launch_bounds__(256, 4) void decode_kernel(
    const float* __restrict__ W_dec,   // (16384 x 12288)
    const float* __restrict__ b_dec,
    const float* __restrict__ x,
    const float* __restrict__ sel_val,
    const int*   __restrict__ sel_idx,
    float* __restrict__ xhat,          // d_out + 1
    float* __restrict__ out0)
{
    __shared__ float sv[K_];
    __shared__ int   si[K_];
    __shared__ float wsum[4];

    const int t     = threadIdx.x;
    const int blk   = blockIdx.x;
    const int b     = blk / 12;
    const int chunk = blk - b * 12;

    if (t < K_) { sv[t] = sel_val[(b << 5) + t]; si[t] = sel_idx[(b << 5) + t]; }
    __syncthreads();

    const int e = chunk * 1024 + t * 4;
    float4 acc = *(const float4*)&b_dec[e];
    #pragma unroll 8
    for (int j = 0; j < K_; ++j) {
        const float val = sv[j];
        const float4 wd = *(const float4*)&W_dec[(size_t)si[j] * TD + e];
        acc.x += val * wd.x;
        acc.y += val * wd.y;
        acc.z += val * wd.z;
        acc.w += val * wd.w;
    }

    const size_t xo = (size_t)b * TD + e;
    xhat[xo + 0] = acc.x;
    xhat[xo + 1] = acc.y;
    xhat[xo + 2] = acc.z;
    xhat[xo + 3] = acc.w;

    const float4 xv = *(const float4*)&x[xo];
    float dx = acc.x - xv.x, dy = acc.y - xv.y;
    float dz = acc.z - xv.z, dw = acc.w - xv.w;
    float ss = dx * dx + dy * dy + dz * dz + dw * dw;
    #pragma unroll
    for (int off = 32; off > 0; off >>= 1) ss += __shfl_down(ss, off, 64);
    if ((t & 63) == 0) wsum[t >> 6] = ss;
    __syncthreads();
    if (t == 0)
        atomicAdd(out0, (wsum[0] + wsum[1] + wsum[2] + wsum[3]) * (1.0f / 512.0f));
}

extern "C" void kernel_launch(void* const* d_in, const int* in_sizes, int n_in,
                              void* d_out, int out_size, void* d_ws, size_t ws_size,
                              hipStream_t stream) {
    const float* x      = (const float*)d_in[0];
    const float* conv_w = (const float*)d_in[1];
    const float* b_enc  = (const float*)d_in[2];
    const float* W_dec  = (const float*)d_in[3];
    const float* b_dec  = (const float*)d_in[4];

    float* out  = (float*)d_out;
    float* xhat = out + 1;                        // (32,16,768)
    float* z    = out + 1 + 393216;               // (32,16384)

    float* partial_enc = (float*)d_ws;                         // 16.8 MB
    float* cand_val    = (float*)((char*)d_ws + (20u << 20));  // 32 KB
    int*   cand_idx    = (int*)  ((char*)d_ws + (20u << 20) + (64u << 10));
    float* sel_val     = (float*)((char*)d_ws + (21u << 20));
    int*   sel_idx     = (int*)  ((char*)d_ws + (21u << 20) + 4096);

    enc_kernel         <<<256, 256, 0, stream>>>(x, conv_w, partial_enc);
    combine_topk_kernel<<<256, 256, 0, stream>>>(partial_enc, b_enc, z,
                                                 cand_val, cand_idx, out);
    select_kernel      <<<32,  256, 0, stream>>>(cand_val, cand_idx, z,
                                                 sel_val, sel_idx);
    decode_kernel      <<<384, 256, 0, stream>>>(W_dec, b_dec, x,
                                                 sel_val, sel_idx, xhat, out);
}

// Round 5
// 123.895 us; speedup vs baseline: 1.2912x; 1.2912x over previous
//
#include <hip/hip_runtime.h>
#include <hip/hip_bf16.h>
#include <float.h>

#define DIN   768
#define DSAE  16384
#define K_    32
#define KTOT  2304
#define TD    12288   // 16*768
#define KSPLIT 8
#define KLEN   288    // KTOT/KSPLIT
#define KC     32
#define NCH    9      // KLEN/KC
#define SB     256    // s-rows per enc block (2 blocks/CU)
#define WSTR   36

#define FMA4(ACC, S, A) { ACC.x += (S) * (A).x; ACC.y += (S) * (A).y; \
                          ACC.z += (S) * (A).z; ACC.w += (S) * (A).w; }

__device__ __forceinline__ int aidx(int k, int b) {   // XOR-swizzled A_lds layout
    return k * 32 + (b ^ ((k & 7) << 2));
}

// ---------------- Kernel 1: prep — build A_T[k][b], k = d*3+j ----------------
__global__ __launch_bounds__(256) void prep_kernel(const float* __restrict__ x,
                                                   float* __restrict__ A_T) {
    int g = blockIdx.x * 256 + threadIdx.x;      // 0..24575
    int b = g / DIN;
    int d = g - b * DIN;
    const float* xp = x + (size_t)b * TD + d;
    float S = 0.f;
    float x0 = xp[0];
    float xl = xp[15 * DIN];
    #pragma unroll
    for (int t = 0; t < 16; ++t) S += xp[t * DIN];
    int base = d * 96 + b;                       // (d*3+j)*32 + b
    A_T[base]      = S - xl;                     // j=0
    A_T[base + 32] = S;                          // j=1
    A_T[base + 64] = S - x0;                     // j=2
}

// ---------------- Kernel 2: encode GEMM (256s x 32b tile, 2 blocks/CU) ----------------
// grid = 64 s-tiles x 8 k-splits = 512. wave w: b = 8w..8w+7; lane l: rows l+64m, m 0..3.
__global__ __launch_bounds__(256, 2) void enc_gemm_kernel(
    const float* __restrict__ W,      // conv_w (16384 x 2304)
    const float* __restrict__ A_T,    // (2304 x 32)
    float* __restrict__ partial)      // (8 x 32 x 16384)
{
    __shared__ float Wt[SB * WSTR];      // 36864 B
    __shared__ float A_lds[KLEN * 32];   // 36864 B (swizzled)

    const int tid  = threadIdx.x;
    const int ks   = blockIdx.x & 7;
    const int s0   = (blockIdx.x >> 3) * SB;
    const int koff = ks * KLEN;
    const int l    = tid & 63;
    const int w    = tid >> 6;

    // W chunk-0 prefetch (8 float4/thread)
    float4 wreg[8];
    #pragma unroll
    for (int i = 0; i < 8; ++i) {
        int f4 = tid + (i << 8);                 // 0..2047
        int row = f4 >> 3, c = (f4 & 7) << 2;
        wreg[i] = *(const float4*)&W[(size_t)(s0 + row) * KTOT + koff + c];
    }

    // stage ENTIRE A-slice once: 288k x 32b = 2304 float4, 9/thread
    {
        const float4* src = (const float4*)&A_T[koff * 32];
        #pragma unroll
        for (int j = 0; j < 9; ++j) {
            int f = tid + (j << 8);              // float4 index
            int k = f >> 3, q = f & 7;
            float4 v = src[f];
            *(float4*)&A_lds[k * 32 + ((q << 2) ^ ((k & 7) << 2))] = v;
        }
    }

    float4 acc0[4], acc1[4];
    #pragma unroll
    for (int m = 0; m < 4; ++m) {
        acc0[m] = make_float4(0.f, 0.f, 0.f, 0.f);
        acc1[m] = make_float4(0.f, 0.f, 0.f, 0.f);
    }

    #pragma unroll 1
    for (int ch = 0; ch < NCH; ++ch) {
        __syncthreads();                         // prev compute done (and A ready at ch0)
        #pragma unroll
        for (int i = 0; i < 8; ++i) {
            int f4 = tid + (i << 8);
            int row = f4 >> 3, c = (f4 & 7) << 2;
            *(float4*)&Wt[row * WSTR + c] = wreg[i];
        }
        __syncthreads();

        if (ch + 1 < NCH) {                      // prefetch next W chunk under compute
            const int kc = (ch + 1) * KC;
            #pragma unroll
            for (int i = 0; i < 8; ++i) {
                int f4 = tid + (i << 8);
                int row = f4 >> 3, c = (f4 & 7) << 2;
                wreg[i] = *(const float4*)&W[(size_t)(s0 + row) * KTOT + koff + kc + c];
            }
        }

        #pragma unroll
        for (int g = 0; g < 8; ++g) {
            const int kk0 = g << 2;
            float4 a0[4], a1[4];
            #pragma unroll
            for (int d = 0; d < 4; ++d) {
                const int k = ch * KC + kk0 + d;
                a0[d] = *(const float4*)&A_lds[aidx(k, w << 3)];        // broadcast
                a1[d] = *(const float4*)&A_lds[aidx(k, (w << 3) + 4)];
            }
            #pragma unroll
            for (int m = 0; m < 4; ++m) {
                float4 wv = *(const float4*)&Wt[(l + (m << 6)) * WSTR + kk0];
                FMA4(acc0[m], wv.x, a0[0]); FMA4(acc0[m], wv.y, a0[1]);
                FMA4(acc0[m], wv.z, a0[2]); FMA4(acc0[m], wv.w, a0[3]);
                FMA4(acc1[m], wv.x, a1[0]); FMA4(acc1[m], wv.y, a1[1]);
                FMA4(acc1[m], wv.z, a1[2]); FMA4(acc1[m], wv.w, a1[3]);
            }
        }
    }

    // partial[ks][b][s], coalesced over l
    float* pb = partial + (size_t)(ks * 32 + (w << 3)) * DSAE + s0 + l;
    #pragma unroll
    for (int m = 0; m < 4; ++m) {
        const int so = m << 6;
        pb[(size_t)0 * DSAE + so] = acc0[m].x;
        pb[(size_t)1 * DSAE + so] = acc0[m].y;
        pb[(size_t)2 * DSAE + so] = acc0[m].z;
        pb[(size_t)3 * DSAE + so] = acc0[m].w;
        pb[(size_t)4 * DSAE + so] = acc1[m].x;
        pb[(size_t)5 * DSAE + so] = acc1[m].y;
        pb[(size_t)6 * DSAE + so] = acc1[m].z;
        pb[(size_t)7 * DSAE + so] = acc1[m].w;
    }
}

// ---------------- Kernel 3: combine K-split partials + bias (streaming) ----------------
__global__ __launch_bounds__(256) void combine_kernel(const float* __restrict__ partial,
                                                      const float* __restrict__ b_enc,
                                                      float* __restrict__ pre,
                                                      float* __restrict__ out0) {
    int g  = blockIdx.x * 256 + threadIdx.x;     // float4 index, 0..131071
    int b  = g >> 12;
    int s4 = g & 4095;
    const float4* p = (const float4*)partial;
    float4 acc = p[(size_t)b * 4096 + s4];
    #pragma unroll
    for (int ks = 1; ks < KSPLIT; ++ks) {
        float4 v = p[(size_t)(ks * 32 + b) * 4096 + s4];
        acc.x += v.x; acc.y += v.y; acc.z += v.z; acc.w += v.w;
    }
    float4 be = ((const float4*)b_enc)[s4];
    acc.x += be.x; acc.y += be.y; acc.z += be.z; acc.w += be.w;
    ((float4*)pre)[(size_t)b * 4096 + s4] = acc;
    if (g == 0) *out0 = 0.f;
}

// ---------------- Kernel 4: top-k via 4-pass radix select (exact lax.top_k) ----------------
__global__ __launch_bounds__(1024, 1) void topk_kernel(
    float* __restrict__ z,            // in: pre (32 x DSAE); out: sparse z
    float* __restrict__ sel_val,
    int*   __restrict__ sel_idx)
{
    __shared__ unsigned hist[256];
    __shared__ unsigned gsfx[65];
    __shared__ unsigned sfx[257];
    __shared__ int      sdelta;
    __shared__ unsigned scnt;
    __shared__ int      l_idx[K_];
    __shared__ float    l_val[K_];
    __shared__ int      eq_min;

    const int t = threadIdx.x;
    const int b = blockIdx.x;
    float* zrow = z + (size_t)b * DSAE;

    float v[16]; unsigned u[16];
    #pragma unroll
    for (int i = 0; i < 16; ++i) {
        float f = zrow[t + (i << 10)];
        v[i] = f;
        unsigned xb = __float_as_uint(f);
        u[i] = (xb & 0x80000000u) ? ~xb : (xb | 0x80000000u);
    }

    unsigned prefix = 0, pmask = 0;
    int need = K_;

    for (int p = 0; p < 4; ++p) {
        const int shift = 24 - 8 * p;
        if (t < 256) hist[t] = 0;
        __syncthreads();
        #pragma unroll
        for (int i = 0; i < 16; ++i)
            if ((u[i] & pmask) == prefix)
                atomicAdd(&hist[(u[i] >> shift) & 255u], 1u);
        __syncthreads();
        if (t < 64) {
            unsigned s4 = hist[4*t] + hist[4*t+1] + hist[4*t+2] + hist[4*t+3];
            #pragma unroll
            for (int off = 1; off < 64; off <<= 1) {
                unsigned o = __shfl_down(s4, off, 64);
                if (t + off < 64) s4 += o;
            }
            gsfx[t] = s4;
            if (t == 0) gsfx[64] = 0;
        }
        __syncthreads();
        if (t < 256) {
            int q = t >> 2;
            unsigned acc = gsfx[q + 1];
            for (int d = 4*q + 3; d >= t; --d) acc += hist[d];
            sfx[t] = acc;
            if (t == 0) sfx[256] = 0;
        }
        __syncthreads();
        if (t < 256) {
            if (sfx[t] >= (unsigned)need && sfx[t + 1] < (unsigned)need) sdelta = t;
        }
        __syncthreads();
        const int dlt = sdelta;
        need  -= (int)sfx[dlt + 1];
        prefix |= ((unsigned)dlt) << shift;
        pmask  |= 0xFFu << shift;
        __syncthreads();
    }

    const unsigned ustar = prefix;
    if (t == 0) scnt = 0;
    __syncthreads();

    unsigned eqmask = 0;
    #pragma unroll
    for (int i = 0; i < 16; ++i) {
        int idx = t + (i << 10);
        if (u[i] > ustar) {
            unsigned s = atomicAdd(&scnt, 1u);
            l_idx[s] = idx; l_val[s] = v[i];
        } else if (u[i] == ustar) {
            eqmask |= (1u << i);
        }
    }
    __syncthreads();
    const int needf = need;
    for (int r = 0; r < needf; ++r) {
        if (t == 0) eq_min = 0x7FFFFFFF;
        __syncthreads();
        #pragma unroll
        for (int i = 0; i < 16; ++i)
            if (eqmask & (1u << i)) atomicMin(&eq_min, t + (i << 10));
        __syncthreads();
        #pragma unroll
        for (int i = 0; i < 16; ++i)
            if ((eqmask & (1u << i)) && (t + (i << 10) == eq_min)) {
                eqmask &= ~(1u << i);
                unsigned s = atomicAdd(&scnt, 1u);
                l_idx[s] = eq_min; l_val[s] = v[i];
            }
        __syncthreads();
    }

    #pragma unroll
    for (int i = 0; i < 16; ++i) zrow[t + (i << 10)] = 0.f;
    __syncthreads();
    if (t == 0) {
        for (int a = 1; a < K_; ++a) {
            int ia = l_idx[a]; float va = l_val[a]; int c = a - 1;
            while (c >= 0 && l_idx[c] > ia) {
                l_idx[c+1] = l_idx[c]; l_val[c+1] = l_val[c]; --c;
            }
            l_idx[c+1] = ia; l_val[c+1] = va;
        }
    }
    __syncthreads();
    if (t < K_) {
        float val = l_val[t] > 0.f ? l_val[t] : 0.f;
        zrow[l_idx[t]] = val;
        sel_val[(b << 5) + t] = val;
        sel_idx[(b << 5) + t] = l_idx[t];
    }
}

// ---------------- Kernel 5: sparse decode + fused sq-err, atomic loss ----------------
__global__ __launch_bounds__(256, 4) void decode_kernel(
    const float* __restrict__ W_dec,
    const float* __restrict__ b_dec,
    const float* __restrict__ x,
    const float* __restrict__ sel_val,
    const int*   __restrict__ sel_idx,
    float* __restrict__ xhat,          // d_out + 1
    float* __restrict__ out0)
{
    __shared__ float sv[K_];
    __shared__ int   si[K_];
    __shared__ float wsum[4];

    const int t     = threadIdx.x;
    const int blk   = blockIdx.x;
    const int b     = blk / 12;
    const int chunk = blk - b * 12;

    if (t < K_) { sv[t] = sel_val[(b << 5) + t]; si[t] = sel_idx[(b << 5) + t]; }
    __syncthreads();

    const int e = chunk * 1024 + t * 4;
    float4 acc = *(const float4*)&b_dec[e];
    #pragma unroll 8
    for (int j = 0; j < K_; ++j) {
        const float val = sv[j];
        const float4 wd = *(const float4*)&W_dec[(size_t)si[j] * TD + e];
        acc.x += val * wd.x;
        acc.y += val * wd.y;
        acc.z += val * wd.z;
        acc.w += val * wd.w;
    }

    const size_t xo = (size_t)b * TD + e;
    xhat[xo + 0] = acc.x;
    xhat[xo + 1] = acc.y;
    xhat[xo + 2] = acc.z;
    xhat[xo + 3] = acc.w;

    const float4 xv = *(const float4*)&x[xo];
    float dx = acc.x - xv.x, dy = acc.y - xv.y;
    float dz = acc.z - xv.z, dw = acc.w - xv.w;
    float ss = dx * dx + dy * dy + dz * dz + dw * dw;
    #pragma unroll
    for (int off = 32; off > 0; off >>= 1) ss += __shfl_down(ss, off, 64);
    if ((t & 63) == 0) wsum[t >> 6] = ss;
    __syncthreads();
    if (t == 0)
        atomicAdd(out0, (wsum[0] + wsum[1] + wsum[2] + wsum[3]) * (1.0f / 512.0f));
}

extern "C" void kernel_launch(void* const* d_in, const int* in_sizes, int n_in,
                              void* d_out, int out_size, void* d_ws, size_t ws_size,
                              hipStream_t stream) {
    const float* x      = (const float*)d_in[0];
    const float* conv_w = (const float*)d_in[1];
    const float* b_enc  = (const float*)d_in[2];
    const float* W_dec  = (const float*)d_in[3];
    const float* b_dec  = (const float*)d_in[4];

    float* out  = (float*)d_out;
    float* xhat = out + 1;                        // (32,16,768)
    float* z    = out + 1 + 393216;               // (32,16384) — holds pre then sparse z

    float* partial_enc = (float*)d_ws;                          // 16.8 MB
    float* A_T         = (float*)((char*)d_ws + (20u << 20));   // 288 KB
    float* sel_val     = (float*)((char*)d_ws + (21u << 20));
    int*   sel_idx     = (int*)  ((char*)d_ws + (21u << 20) + 4096);

    prep_kernel    <<<96,  256,  0, stream>>>(x, A_T);
    enc_gemm_kernel<<<512, 256,  0, stream>>>(conv_w, A_T, partial_enc);
    combine_kernel <<<512, 256,  0, stream>>>(partial_enc, b_enc, z, out);
    topk_kernel    <<<32,  1024, 0, stream>>>(z, sel_val, sel_idx);
    decode_kernel  <<<384, 256,  0, stream>>>(W_dec, b_dec, x, sel_val, sel_idx, xhat, out);
}